// Round 2
// baseline (606.020 us; speedup 1.0000x reference)
//
#include <hip/hip_runtime.h>
#include <hip/hip_bf16.h>
#include <cstdint>
#include <cstddef>

#define HH 1024
#define BB 8
#define TT 2048
#define MM (BB*TT)   // 16384

typedef __attribute__((ext_vector_type(8))) short bf16x8;
typedef __attribute__((ext_vector_type(4))) float f32x4;

__device__ __forceinline__ unsigned short f2bf(float f) {
  union { float f; unsigned u; } v; v.f = f;
  return (unsigned short)((v.u + 0x7fffu + ((v.u >> 16) & 1u)) >> 16);  // RNE
}
__device__ __forceinline__ float bf2f(unsigned short s) {
  union { float f; unsigned u; } v; v.u = ((unsigned)s) << 16;
  return v.f;
}

__device__ __forceinline__ void load_lds16(const void* g, void* l) {
  __builtin_amdgcn_global_load_lds((const __attribute__((address_space(1))) void*)g,
                                   (__attribute__((address_space(3))) void*)l,
                                   16, 0, 0);
}

// ---------------- weight fp32 -> bf16 ----------------
__global__ __launch_bounds__(256) void conv_w(const float* __restrict__ Wk,
    const float* __restrict__ Wv, const float* __restrict__ Wr,
    const float* __restrict__ Wo, unsigned short* __restrict__ dst) {
  const int i = (blockIdx.x * 256 + threadIdx.x) * 4;
  const float* src = blockIdx.y == 0 ? Wk : blockIdx.y == 1 ? Wv : blockIdx.y == 2 ? Wr : Wo;
  const float4 v = *(const float4*)(src + i);
  ushort4 o; o.x = f2bf(v.x); o.y = f2bf(v.y); o.z = f2bf(v.z); o.w = f2bf(v.w);
  *(ushort4*)(dst + (size_t)blockIdx.y * HH * HH + i) = o;
}

// ---------------- time-shift + mix -> bf16 kin/vin/rin ----------------
__global__ __launch_bounds__(256) void mix_kernel(const float* __restrict__ x,
    const float* __restrict__ tmk, const float* __restrict__ tmv, const float* __restrict__ tmr,
    unsigned short* __restrict__ kin, unsigned short* __restrict__ vin,
    unsigned short* __restrict__ rin) {
  const int gid = blockIdx.x * 256 + threadIdx.x;
  const size_t e0 = (size_t)gid * 4;
  const int h = (int)(e0 & (HH - 1));
  const int t = (int)((e0 >> 10) & (TT - 1));
  const float4 xv = *(const float4*)(x + e0);
  float4 sv = make_float4(0.f, 0.f, 0.f, 0.f);
  if (t != 0) sv = *(const float4*)(x + e0 - HH);
  const float4 k4 = *(const float4*)(tmk + h);
  const float4 v4 = *(const float4*)(tmv + h);
  const float4 r4 = *(const float4*)(tmr + h);
  ushort4 ko, vo, ro;
  ko.x = f2bf(sv.x + k4.x * (xv.x - sv.x)); ko.y = f2bf(sv.y + k4.y * (xv.y - sv.y));
  ko.z = f2bf(sv.z + k4.z * (xv.z - sv.z)); ko.w = f2bf(sv.w + k4.w * (xv.w - sv.w));
  vo.x = f2bf(sv.x + v4.x * (xv.x - sv.x)); vo.y = f2bf(sv.y + v4.y * (xv.y - sv.y));
  vo.z = f2bf(sv.z + v4.z * (xv.z - sv.z)); vo.w = f2bf(sv.w + v4.w * (xv.w - sv.w));
  ro.x = f2bf(sv.x + r4.x * (xv.x - sv.x)); ro.y = f2bf(sv.y + r4.y * (xv.y - sv.y));
  ro.z = f2bf(sv.z + r4.z * (xv.z - sv.z)); ro.w = f2bf(sv.w + r4.w * (xv.w - sv.w));
  *(ushort4*)(kin + e0) = ko;
  *(ushort4*)(vin + e0) = vo;
  *(ushort4*)(rin + e0) = ro;
}

// ---------------- GEMM core: C[128x128] tile, A[M,K]*B[N,K]^T, bf16 ----------------
// block = 256 threads = 4 waves in 2x2; each wave 64x64 = 4x4 frags of 16x16x32 MFMA.
__device__ __forceinline__ void gemm_core(const unsigned short* __restrict__ Ag,
                                          const unsigned short* __restrict__ Bg,
                                          int m0, int n0,
                                          unsigned short* As, unsigned short* Bs,
                                          f32x4 acc[4][4]) {
  const int tid = threadIdx.x;
  const int lane = tid & 63;
  const int w = tid >> 6;
  const int K = HH;
  // staging: tile = 128 rows x 32 cols bf16 = 8 KiB = 512 chunks of 16B; 2 issues/thread
  const int c0 = w * 64 + lane;
  const int c1 = 256 + c0;
  const unsigned short* ga0 = Ag + (size_t)(m0 + (c0 >> 2)) * K + (c0 & 3) * 8;
  const unsigned short* ga1 = Ag + (size_t)(m0 + (c1 >> 2)) * K + (c1 & 3) * 8;
  const unsigned short* gb0 = Bg + (size_t)(n0 + (c0 >> 2)) * K + (c0 & 3) * 8;
  const unsigned short* gb1 = Bg + (size_t)(n0 + (c1 >> 2)) * K + (c1 & 3) * 8;
  unsigned short* la0 = As + (size_t)w * 512;         // wave-uniform LDS base
  unsigned short* la1 = As + (size_t)(4 + w) * 512;
  unsigned short* lb0 = Bs + (size_t)w * 512;
  unsigned short* lb1 = Bs + (size_t)(4 + w) * 512;
  const int wm = w >> 1, wn = w & 1;
  const int fr = lane & 15, fq = lane >> 4;
  const int aoff = (wm * 64 + fr) * 32 + fq * 8;
  const int boff = (wn * 64 + fr) * 32 + fq * 8;

  for (int kt = 0; kt < K; kt += 32) {
    load_lds16(ga0 + kt, la0);
    load_lds16(ga1 + kt, la1);
    load_lds16(gb0 + kt, lb0);
    load_lds16(gb1 + kt, lb1);
    __syncthreads();   // drains vmcnt(0) then barrier
    bf16x8 af[4], bfr[4];
#pragma unroll
    for (int i = 0; i < 4; i++) af[i] = *(const bf16x8*)(As + aoff + i * (16 * 32));
#pragma unroll
    for (int j = 0; j < 4; j++) bfr[j] = *(const bf16x8*)(Bs + boff + j * (16 * 32));
#pragma unroll
    for (int i = 0; i < 4; i++)
#pragma unroll
      for (int j = 0; j < 4; j++)
        acc[i][j] = __builtin_amdgcn_mfma_f32_16x16x32_bf16(af[i], bfr[j], acc[i][j], 0, 0, 0);
    __syncthreads();   // protect LDS before next stage
  }
}

// r = sigmoid(rin @ Wr^T) -> bf16
__global__ __launch_bounds__(256) void gemm_r(const unsigned short* __restrict__ rin,
    const unsigned short* __restrict__ Wrb, unsigned short* __restrict__ rb) {
  __shared__ unsigned short As[128 * 32];
  __shared__ unsigned short Bs[128 * 32];
  const int bn = blockIdx.x & 7, bm = blockIdx.x >> 3;
  const int m0 = bm * 128, n0 = bn * 128;
  f32x4 acc[4][4] = {};
  gemm_core(rin, Wrb, m0, n0, As, Bs, acc);
  const int lane = threadIdx.x & 63, w = threadIdx.x >> 6;
  const int wm = w >> 1, wn = w & 1, fr = lane & 15, fq = lane >> 4;
#pragma unroll
  for (int i = 0; i < 4; i++)
#pragma unroll
    for (int j = 0; j < 4; j++)
#pragma unroll
      for (int rr = 0; rr < 4; rr++) {
        const int row = m0 + wm * 64 + i * 16 + fq * 4 + rr;
        const int col = n0 + wn * 64 + j * 16 + fr;
        const float s = 1.0f / (1.0f + __expf(-acc[i][j][rr]));
        rb[(size_t)row * HH + col] = f2bf(s);
      }
}

// z=0: k = kin @ Wk^T -> fp32 (staged in d_out); z=1: v = vin @ Wv^T -> bf16
__global__ __launch_bounds__(256) void gemm_kv(const unsigned short* __restrict__ kin,
    const unsigned short* __restrict__ vin, const unsigned short* __restrict__ Wbf,
    float* __restrict__ kf, unsigned short* __restrict__ vb) {
  __shared__ unsigned short As[128 * 32];
  __shared__ unsigned short Bs[128 * 32];
  const int z = blockIdx.z;
  const unsigned short* Ag = z == 0 ? kin : vin;
  const unsigned short* Bg = Wbf + (size_t)z * HH * HH;
  const int bn = blockIdx.x & 7, bm = blockIdx.x >> 3;
  const int m0 = bm * 128, n0 = bn * 128;
  f32x4 acc[4][4] = {};
  gemm_core(Ag, Bg, m0, n0, As, Bs, acc);
  const int lane = threadIdx.x & 63, w = threadIdx.x >> 6;
  const int wm = w >> 1, wn = w & 1, fr = lane & 15, fq = lane >> 4;
  if (z == 0) {
#pragma unroll
    for (int i = 0; i < 4; i++)
#pragma unroll
      for (int j = 0; j < 4; j++)
#pragma unroll
        for (int rr = 0; rr < 4; rr++) {
          const int row = m0 + wm * 64 + i * 16 + fq * 4 + rr;
          const int col = n0 + wn * 64 + j * 16 + fr;
          kf[(size_t)row * HH + col] = acc[i][j][rr];
        }
  } else {
#pragma unroll
    for (int i = 0; i < 4; i++)
#pragma unroll
      for (int j = 0; j < 4; j++)
#pragma unroll
        for (int rr = 0; rr < 4; rr++) {
          const int row = m0 + wm * 64 + i * 16 + fq * 4 + rr;
          const int col = n0 + wn * 64 + j * 16 + fr;
          vb[(size_t)row * HH + col] = f2bf(acc[i][j][rr]);
        }
  }
}

// out = rwkv @ Wo^T + bo  (fp32 out)
__global__ __launch_bounds__(256) void gemm_o(const unsigned short* __restrict__ Ag,
    const unsigned short* __restrict__ Bg, const float* __restrict__ bias,
    float* __restrict__ C) {
  __shared__ unsigned short As[128 * 32];
  __shared__ unsigned short Bs[128 * 32];
  const int bn = blockIdx.x & 7, bm = blockIdx.x >> 3;
  const int m0 = bm * 128, n0 = bn * 128;
  f32x4 acc[4][4] = {};
  gemm_core(Ag, Bg, m0, n0, As, Bs, acc);
  const int lane = threadIdx.x & 63, w = threadIdx.x >> 6;
  const int wm = w >> 1, wn = w & 1, fr = lane & 15, fq = lane >> 4;
#pragma unroll
  for (int i = 0; i < 4; i++)
#pragma unroll
    for (int j = 0; j < 4; j++)
#pragma unroll
      for (int rr = 0; rr < 4; rr++) {
        const int row = m0 + wm * 64 + i * 16 + fq * 4 + rr;
        const int col = n0 + wn * 64 + j * 16 + fr;
        C[(size_t)row * HH + col] = acc[i][j][rr] + bias[col];
      }
}

// ---------------- WKV recurrence: one thread per (b,h) channel ----------------
__global__ __launch_bounds__(256) void wkv_kernel(const float* __restrict__ k,
    const unsigned short* __restrict__ v, const unsigned short* __restrict__ r,
    const float* __restrict__ time_decay, const float* __restrict__ time_first,
    unsigned short* __restrict__ rwkv) {
  const int gid = blockIdx.x * 256 + threadIdx.x;  // 0..8191
  const int h = gid & (HH - 1);
  const int b = gid >> 10;
  const float td = __expf(-__expf(time_decay[h]));
  const float tf = time_first[h];
  size_t idx = (size_t)b * TT * HH + h;
  float num = 0.f, den = 0.f;
#pragma unroll 8
  for (int t = 0; t < TT; ++t, idx += HH) {
    const float kt = k[idx];
    const float vt = bf2f(v[idx]);
    const float rt = bf2f(r[idx]);
    const float e = __expf(tf + kt);
    const float inv = __builtin_amdgcn_rcpf(den + e);   // den+e > 0 always
    const float outv = (num + e * vt) * inv;
    const float ek = __expf(kt);
    num = td * num + ek * vt;
    den = td * den + ek;
    rwkv[idx] = f2bf(outv * rt);
  }
}

extern "C" void kernel_launch(void* const* d_in, const int* in_sizes, int n_in,
                              void* d_out, int out_size, void* d_ws, size_t ws_size,
                              hipStream_t stream) {
  (void)in_sizes; (void)n_in; (void)out_size; (void)ws_size;
  const float* x    = (const float*)d_in[0];
  const float* tdec = (const float*)d_in[1];
  const float* tfst = (const float*)d_in[2];
  const float* tmk  = (const float*)d_in[3];
  const float* tmv  = (const float*)d_in[4];
  const float* tmr  = (const float*)d_in[5];
  const float* Wk   = (const float*)d_in[6];
  const float* Wv   = (const float*)d_in[7];
  const float* Wr   = (const float*)d_in[8];
  const float* Wo   = (const float*)d_in[9];
  const float* bo   = (const float*)d_in[10];
  float* out = (float*)d_out;

  char* ws = (char*)d_ws;
  const size_t MiB = (size_t)1 << 20;
  unsigned short* Wbf = (unsigned short*)(ws);             //   8 MiB: Wk,Wv,Wr,Wo bf16
  unsigned short* kin = (unsigned short*)(ws + 8 * MiB);   //  32 MiB
  unsigned short* vin = (unsigned short*)(ws + 40 * MiB);  //  32 MiB
  unsigned short* rin = (unsigned short*)(ws + 72 * MiB);  //  32 MiB
  unsigned short* rb  = (unsigned short*)(ws + 104 * MiB); //  32 MiB  (peak 136 MiB)
  unsigned short* vb   = rin;   // rin dead after gemm_r; reuse for v bf16
  unsigned short* rwkv = kin;   // kin dead after gemm_kv; reuse
  float* kf = out;              // k fp32 staged in d_out; overwritten by gemm_o later

  hipLaunchKernelGGL(conv_w, dim3(1024, 4), dim3(256), 0, stream, Wk, Wv, Wr, Wo, Wbf);
  hipLaunchKernelGGL(mix_kernel, dim3(16384), dim3(256), 0, stream,
                     x, tmk, tmv, tmr, kin, vin, rin);
  hipLaunchKernelGGL(gemm_r, dim3(1024), dim3(256), 0, stream,
                     rin, Wbf + (size_t)2 * HH * HH, rb);
  hipLaunchKernelGGL(gemm_kv, dim3(1024, 1, 2), dim3(256), 0, stream,
                     kin, vin, Wbf, kf, vb);
  hipLaunchKernelGGL(wkv_kernel, dim3(32), dim3(256), 0, stream,
                     kf, vb, rb, tdec, tfst, rwkv);
  hipLaunchKernelGGL(gemm_o, dim3(1024), dim3(256), 0, stream,
                     rwkv, Wbf + (size_t)3 * HH * HH, bo, out);
}

// Round 3
// 440.698 us; speedup vs baseline: 1.3751x; 1.3751x over previous
//
#include <hip/hip_runtime.h>
#include <hip/hip_bf16.h>
#include <cstdint>
#include <cstddef>

#define HH 1024
#define BB 8
#define TT 2048
#define MM (BB*TT)   // 16384
#define CC 64        // wkv chunks
#define LL (TT/CC)   // 32 steps per chunk

typedef __attribute__((ext_vector_type(8))) short bf16x8;
typedef __attribute__((ext_vector_type(4))) float f32x4;

__device__ __forceinline__ unsigned short f2bf(float f) {
  union { float f; unsigned u; } v; v.f = f;
  return (unsigned short)((v.u + 0x7fffu + ((v.u >> 16) & 1u)) >> 16);  // RNE
}
__device__ __forceinline__ float bf2f(unsigned short s) {
  union { float f; unsigned u; } v; v.u = ((unsigned)s) << 16;
  return v.f;
}

__device__ __forceinline__ void load_lds16(const void* g, void* l) {
  __builtin_amdgcn_global_load_lds((const __attribute__((address_space(1))) void*)g,
                                   (__attribute__((address_space(3))) void*)l,
                                   16, 0, 0);
}

// ---------------- weight fp32 -> bf16 ----------------
__global__ __launch_bounds__(256) void conv_w(const float* __restrict__ Wk,
    const float* __restrict__ Wv, const float* __restrict__ Wr,
    const float* __restrict__ Wo, unsigned short* __restrict__ dst) {
  const int i = (blockIdx.x * 256 + threadIdx.x) * 4;
  const float* src = blockIdx.y == 0 ? Wk : blockIdx.y == 1 ? Wv : blockIdx.y == 2 ? Wr : Wo;
  const float4 v = *(const float4*)(src + i);
  ushort4 o; o.x = f2bf(v.x); o.y = f2bf(v.y); o.z = f2bf(v.z); o.w = f2bf(v.w);
  *(ushort4*)(dst + (size_t)blockIdx.y * HH * HH + i) = o;
}

// ---------------- time-shift + mix -> bf16 kin/vin/rin ----------------
__global__ __launch_bounds__(256) void mix_kernel(const float* __restrict__ x,
    const float* __restrict__ tmk, const float* __restrict__ tmv, const float* __restrict__ tmr,
    unsigned short* __restrict__ kin, unsigned short* __restrict__ vin,
    unsigned short* __restrict__ rin) {
  const int gid = blockIdx.x * 256 + threadIdx.x;
  const size_t e0 = (size_t)gid * 4;
  const int h = (int)(e0 & (HH - 1));
  const int t = (int)((e0 >> 10) & (TT - 1));
  const float4 xv = *(const float4*)(x + e0);
  float4 sv = make_float4(0.f, 0.f, 0.f, 0.f);
  if (t != 0) sv = *(const float4*)(x + e0 - HH);
  const float4 k4 = *(const float4*)(tmk + h);
  const float4 v4 = *(const float4*)(tmv + h);
  const float4 r4 = *(const float4*)(tmr + h);
  ushort4 ko, vo, ro;
  ko.x = f2bf(sv.x + k4.x * (xv.x - sv.x)); ko.y = f2bf(sv.y + k4.y * (xv.y - sv.y));
  ko.z = f2bf(sv.z + k4.z * (xv.z - sv.z)); ko.w = f2bf(sv.w + k4.w * (xv.w - sv.w));
  vo.x = f2bf(sv.x + v4.x * (xv.x - sv.x)); vo.y = f2bf(sv.y + v4.y * (xv.y - sv.y));
  vo.z = f2bf(sv.z + v4.z * (xv.z - sv.z)); vo.w = f2bf(sv.w + v4.w * (xv.w - sv.w));
  ro.x = f2bf(sv.x + r4.x * (xv.x - sv.x)); ro.y = f2bf(sv.y + r4.y * (xv.y - sv.y));
  ro.z = f2bf(sv.z + r4.z * (xv.z - sv.z)); ro.w = f2bf(sv.w + r4.w * (xv.w - sv.w));
  *(ushort4*)(kin + e0) = ko;
  *(ushort4*)(vin + e0) = vo;
  *(ushort4*)(rin + e0) = ro;
}

// ---------------- GEMM core: C[128x128] tile, A[M,K]*B[N,K]^T, bf16 ----------------
__device__ __forceinline__ void gemm_core(const unsigned short* __restrict__ Ag,
                                          const unsigned short* __restrict__ Bg,
                                          int m0, int n0,
                                          unsigned short* As, unsigned short* Bs,
                                          f32x4 acc[4][4]) {
  const int tid = threadIdx.x;
  const int lane = tid & 63;
  const int w = tid >> 6;
  const int K = HH;
  const int c0 = w * 64 + lane;
  const int c1 = 256 + c0;
  const unsigned short* ga0 = Ag + (size_t)(m0 + (c0 >> 2)) * K + (c0 & 3) * 8;
  const unsigned short* ga1 = Ag + (size_t)(m0 + (c1 >> 2)) * K + (c1 & 3) * 8;
  const unsigned short* gb0 = Bg + (size_t)(n0 + (c0 >> 2)) * K + (c0 & 3) * 8;
  const unsigned short* gb1 = Bg + (size_t)(n0 + (c1 >> 2)) * K + (c1 & 3) * 8;
  unsigned short* la0 = As + (size_t)w * 512;         // wave-uniform LDS base
  unsigned short* la1 = As + (size_t)(4 + w) * 512;
  unsigned short* lb0 = Bs + (size_t)w * 512;
  unsigned short* lb1 = Bs + (size_t)(4 + w) * 512;
  const int wm = w >> 1, wn = w & 1;
  const int fr = lane & 15, fq = lane >> 4;
  const int aoff = (wm * 64 + fr) * 32 + fq * 8;
  const int boff = (wn * 64 + fr) * 32 + fq * 8;

  for (int kt = 0; kt < K; kt += 32) {
    load_lds16(ga0 + kt, la0);
    load_lds16(ga1 + kt, la1);
    load_lds16(gb0 + kt, lb0);
    load_lds16(gb1 + kt, lb1);
    __syncthreads();
    bf16x8 af[4], bfr[4];
#pragma unroll
    for (int i = 0; i < 4; i++) af[i] = *(const bf16x8*)(As + aoff + i * (16 * 32));
#pragma unroll
    for (int j = 0; j < 4; j++) bfr[j] = *(const bf16x8*)(Bs + boff + j * (16 * 32));
#pragma unroll
    for (int i = 0; i < 4; i++)
#pragma unroll
      for (int j = 0; j < 4; j++)
        acc[i][j] = __builtin_amdgcn_mfma_f32_16x16x32_bf16(af[i], bfr[j], acc[i][j], 0, 0, 0);
    __syncthreads();
  }
}

// r = sigmoid(rin @ Wr^T) -> bf16
__global__ __launch_bounds__(256) void gemm_r(const unsigned short* __restrict__ rin,
    const unsigned short* __restrict__ Wrb, unsigned short* __restrict__ rb) {
  __shared__ unsigned short As[128 * 32];
  __shared__ unsigned short Bs[128 * 32];
  const int bn = blockIdx.x & 7, bm = blockIdx.x >> 3;
  const int m0 = bm * 128, n0 = bn * 128;
  f32x4 acc[4][4] = {};
  gemm_core(rin, Wrb, m0, n0, As, Bs, acc);
  const int lane = threadIdx.x & 63, w = threadIdx.x >> 6;
  const int wm = w >> 1, wn = w & 1, fr = lane & 15, fq = lane >> 4;
#pragma unroll
  for (int i = 0; i < 4; i++)
#pragma unroll
    for (int j = 0; j < 4; j++)
#pragma unroll
      for (int rr = 0; rr < 4; rr++) {
        const int row = m0 + wm * 64 + i * 16 + fq * 4 + rr;
        const int col = n0 + wn * 64 + j * 16 + fr;
        const float s = 1.0f / (1.0f + __expf(-acc[i][j][rr]));
        rb[(size_t)row * HH + col] = f2bf(s);
      }
}

// z=0: k = kin @ Wk^T -> fp32 (staged in d_out); z=1: v = vin @ Wv^T -> bf16
__global__ __launch_bounds__(256) void gemm_kv(const unsigned short* __restrict__ kin,
    const unsigned short* __restrict__ vin, const unsigned short* __restrict__ Wbf,
    float* __restrict__ kf, unsigned short* __restrict__ vb) {
  __shared__ unsigned short As[128 * 32];
  __shared__ unsigned short Bs[128 * 32];
  const int z = blockIdx.z;
  const unsigned short* Ag = z == 0 ? kin : vin;
  const unsigned short* Bg = Wbf + (size_t)z * HH * HH;
  const int bn = blockIdx.x & 7, bm = blockIdx.x >> 3;
  const int m0 = bm * 128, n0 = bn * 128;
  f32x4 acc[4][4] = {};
  gemm_core(Ag, Bg, m0, n0, As, Bs, acc);
  const int lane = threadIdx.x & 63, w = threadIdx.x >> 6;
  const int wm = w >> 1, wn = w & 1, fr = lane & 15, fq = lane >> 4;
  if (z == 0) {
#pragma unroll
    for (int i = 0; i < 4; i++)
#pragma unroll
      for (int j = 0; j < 4; j++)
#pragma unroll
        for (int rr = 0; rr < 4; rr++) {
          const int row = m0 + wm * 64 + i * 16 + fq * 4 + rr;
          const int col = n0 + wn * 64 + j * 16 + fr;
          kf[(size_t)row * HH + col] = acc[i][j][rr];
        }
  } else {
#pragma unroll
    for (int i = 0; i < 4; i++)
#pragma unroll
      for (int j = 0; j < 4; j++)
#pragma unroll
        for (int rr = 0; rr < 4; rr++) {
          const int row = m0 + wm * 64 + i * 16 + fq * 4 + rr;
          const int col = n0 + wn * 64 + j * 16 + fr;
          vb[(size_t)row * HH + col] = f2bf(acc[i][j][rr]);
        }
  }
}

// out = rwkv @ Wo^T + bo  (fp32 out)
__global__ __launch_bounds__(256) void gemm_o(const unsigned short* __restrict__ Ag,
    const unsigned short* __restrict__ Bg, const float* __restrict__ bias,
    float* __restrict__ C) {
  __shared__ unsigned short As[128 * 32];
  __shared__ unsigned short Bs[128 * 32];
  const int bn = blockIdx.x & 7, bm = blockIdx.x >> 3;
  const int m0 = bm * 128, n0 = bn * 128;
  f32x4 acc[4][4] = {};
  gemm_core(Ag, Bg, m0, n0, As, Bs, acc);
  const int lane = threadIdx.x & 63, w = threadIdx.x >> 6;
  const int wm = w >> 1, wn = w & 1, fr = lane & 15, fq = lane >> 4;
#pragma unroll
  for (int i = 0; i < 4; i++)
#pragma unroll
    for (int j = 0; j < 4; j++)
#pragma unroll
      for (int rr = 0; rr < 4; rr++) {
        const int row = m0 + wm * 64 + i * 16 + fq * 4 + rr;
        const int col = n0 + wn * 64 + j * 16 + fr;
        C[(size_t)row * HH + col] = acc[i][j][rr] + bias[col];
      }
}

// ---------------- WKV: chunk-parallel scan over T ----------------
// Pass 1: per (chunk c, b, h) compute local partial sums from zero state.
__global__ __launch_bounds__(256) void wkv_part(const float* __restrict__ k,
    const unsigned short* __restrict__ v, const float* __restrict__ tdec,
    float* __restrict__ pnum, float* __restrict__ pden) {
  const int gid = blockIdx.x * 256 + threadIdx.x;   // 0 .. CC*BB*HH-1
  const int h = gid & (HH - 1);
  const int bh = gid & (BB * HH - 1);
  const int b = (gid >> 10) & (BB - 1);
  const int c = gid >> 13;                           // gid / (BB*HH)
  const float td = __expf(-__expf(tdec[h]));
  size_t idx = (size_t)b * TT * HH + (size_t)(c * LL) * HH + h;
  float num = 0.f, den = 0.f;
#pragma unroll 8
  for (int i = 0; i < LL; ++i, idx += HH) {
    const float ek = __expf(k[idx]);
    const float vt = bf2f(v[idx]);
    num = td * num + ek * vt;
    den = td * den + ek;
  }
  pnum[(size_t)c * (BB * HH) + bh] = num;
  pden[(size_t)c * (BB * HH) + bh] = den;
}

// Pass 2: serial combine over chunks; converts partials -> chunk start states in place.
__global__ __launch_bounds__(256) void wkv_scan(const float* __restrict__ tdec,
    float* __restrict__ pnum, float* __restrict__ pden) {
  const int bh = blockIdx.x * 256 + threadIdx.x;     // 0..8191
  const int h = bh & (HH - 1);
  const float ed = __expf(tdec[h]);
  const float tdL = __expf(-ed * (float)LL);         // td^LL exactly
  float num = 0.f, den = 0.f;
#pragma unroll 8
  for (int c = 0; c < CC; ++c) {
    const size_t o = (size_t)c * (BB * HH) + bh;
    const float tn = pnum[o], td_ = pden[o];
    pnum[o] = num; pden[o] = den;
    num = tdL * num + tn;
    den = tdL * den + td_;
  }
}

// Pass 3: re-stream with correct start state, emit r*wkv bf16.
__global__ __launch_bounds__(256) void wkv_final(const float* __restrict__ k,
    const unsigned short* __restrict__ v, const unsigned short* __restrict__ r,
    const float* __restrict__ tdec, const float* __restrict__ tfst,
    const float* __restrict__ pnum, const float* __restrict__ pden,
    unsigned short* __restrict__ rwkv) {
  const int gid = blockIdx.x * 256 + threadIdx.x;
  const int h = gid & (HH - 1);
  const int bh = gid & (BB * HH - 1);
  const int b = (gid >> 10) & (BB - 1);
  const int c = gid >> 13;
  const float td = __expf(-__expf(tdec[h]));
  const float etf = __expf(tfst[h]);
  float num = pnum[(size_t)c * (BB * HH) + bh];
  float den = pden[(size_t)c * (BB * HH) + bh];
  size_t idx = (size_t)b * TT * HH + (size_t)(c * LL) * HH + h;
#pragma unroll 4
  for (int i = 0; i < LL; ++i, idx += HH) {
    const float ek = __expf(k[idx]);
    const float vt = bf2f(v[idx]);
    const float rt = bf2f(r[idx]);
    const float e = ek * etf;                        // exp(tf + k) = exp(k)*exp(tf)
    const float inv = __builtin_amdgcn_rcpf(den + e);
    const float outv = (num + e * vt) * inv;
    num = td * num + ek * vt;
    den = td * den + ek;
    rwkv[idx] = f2bf(outv * rt);
  }
}

extern "C" void kernel_launch(void* const* d_in, const int* in_sizes, int n_in,
                              void* d_out, int out_size, void* d_ws, size_t ws_size,
                              hipStream_t stream) {
  (void)in_sizes; (void)n_in; (void)out_size; (void)ws_size;
  const float* x    = (const float*)d_in[0];
  const float* tdec = (const float*)d_in[1];
  const float* tfst = (const float*)d_in[2];
  const float* tmk  = (const float*)d_in[3];
  const float* tmv  = (const float*)d_in[4];
  const float* tmr  = (const float*)d_in[5];
  const float* Wk   = (const float*)d_in[6];
  const float* Wv   = (const float*)d_in[7];
  const float* Wr   = (const float*)d_in[8];
  const float* Wo   = (const float*)d_in[9];
  const float* bo   = (const float*)d_in[10];
  float* out = (float*)d_out;

  char* ws = (char*)d_ws;
  const size_t MiB = (size_t)1 << 20;
  unsigned short* Wbf = (unsigned short*)(ws);             //   8 MiB
  unsigned short* kin = (unsigned short*)(ws + 8 * MiB);   //  32 MiB
  unsigned short* vin = (unsigned short*)(ws + 40 * MiB);  //  32 MiB
  unsigned short* rin = (unsigned short*)(ws + 72 * MiB);  //  32 MiB
  unsigned short* rb  = (unsigned short*)(ws + 104 * MiB); //  32 MiB  (peak 136 MiB)
  unsigned short* vb   = rin;                  // rin dead after gemm_r
  unsigned short* rwkv = kin;                  // kin dead after gemm_kv
  float* pnum = (float*)(ws + 40 * MiB);       // vin dead after gemm_kv (2 MiB)
  float* pden = (float*)(ws + 42 * MiB);       // (2 MiB)
  float* kf = out;                             // k fp32 staged in d_out

  hipLaunchKernelGGL(conv_w, dim3(1024, 4), dim3(256), 0, stream, Wk, Wv, Wr, Wo, Wbf);
  hipLaunchKernelGGL(mix_kernel, dim3(16384), dim3(256), 0, stream,
                     x, tmk, tmv, tmr, kin, vin, rin);
  hipLaunchKernelGGL(gemm_r, dim3(1024), dim3(256), 0, stream,
                     rin, Wbf + (size_t)2 * HH * HH, rb);
  hipLaunchKernelGGL(gemm_kv, dim3(1024, 1, 2), dim3(256), 0, stream,
                     kin, vin, Wbf, kf, vb);
  hipLaunchKernelGGL(wkv_part, dim3(2048), dim3(256), 0, stream,
                     kf, vb, tdec, pnum, pden);
  hipLaunchKernelGGL(wkv_scan, dim3(32), dim3(256), 0, stream,
                     tdec, pnum, pden);
  hipLaunchKernelGGL(wkv_final, dim3(2048), dim3(256), 0, stream,
                     kf, vb, rb, tdec, tfst, pnum, pden, rwkv);
  hipLaunchKernelGGL(gemm_o, dim3(1024), dim3(256), 0, stream,
                     rwkv, Wbf + (size_t)3 * HH * HH, bo, out);
}